// Round 4
// baseline (180.013 us; speedup 1.0000x reference)
//
#include <hip/hip_runtime.h>

#define R_MAX 32
#define S_MAX 2
#define DIM_OUT 128
#define N_R (2 * R_MAX + 2)        // 66
#define N_S (2 * S_MAX + 2)        // 6
#define DIM_IN (2 * N_R + 1 + N_S) // 139
#define NBUCKET (2 * R_MAX + 1)    // 65 (bucket in [0,64])

// out[row, d] = W[d, N_R + bucket] + (W[d, R_MAX] + W[d, 2*N_R] + W[d, DIM_IN-1])
// where row = (batch_i * seq + i) * seq + j, bucket = clip(i - j + R_MAX, 0, 2*R_MAX).
__global__ __launch_bounds__(256) void rpe_kernel(const int* __restrict__ p_seq,
                                                  const float* __restrict__ W,
                                                  float4* __restrict__ out,
                                                  unsigned long long n_rows) {
    __shared__ float table[NBUCKET * DIM_OUT]; // 33,280 B

    const unsigned seq = (unsigned)*p_seq;

    // Build bucket->vector table once per block (W is tiny; L2-resident).
    for (int t = threadIdx.x; t < NBUCKET * DIM_OUT; t += blockDim.x) {
        const int b = t >> 7;          // bucket
        const int d = t & (DIM_OUT - 1);
        const float* w = W + (size_t)d * DIM_IN;
        // Match reference association: const = (W_pos[:,R_MAX] + w_mask) + W_chain[:,2S+1]
        const float cst = (w[R_MAX] + w[2 * N_R]) + w[DIM_IN - 1];
        table[t] = w[N_R + b] + cst;
    }
    __syncthreads();

    // 256 threads = 8 row-groups of 32 lanes; each lane stores one float4 (16B).
    const unsigned lane = threadIdx.x & 31;          // column group within the row
    unsigned long long row = (unsigned long long)blockIdx.x * 8 + (threadIdx.x >> 5);
    const unsigned long long rstride = (unsigned long long)gridDim.x * 8;

    // Incremental (i, j) tracking: row = (bi*seq + i)*seq + j. Divide ONCE,
    // then advance j by (rstride % seq) and i by (rstride / seq) per iter.
    unsigned j = (unsigned)(row % seq);
    unsigned long long q = row / seq;
    unsigned i = (unsigned)(q % seq);
    const unsigned dj = (unsigned)(rstride % seq);
    unsigned di = (unsigned)((rstride / seq) % seq);

    for (; row < n_rows; row += rstride) {
        int diff = (int)i - (int)j + R_MAX;
        diff = diff < 0 ? 0 : diff;
        const int b = diff > 2 * R_MAX ? 2 * R_MAX : diff;
        out[row * (DIM_OUT / 4) + lane] =
            *reinterpret_cast<const float4*>(&table[b * DIM_OUT + (lane << 2)]);

        // advance indices
        j += dj;
        unsigned carry = (j >= seq) ? 1u : 0u;
        j -= carry ? seq : 0u;
        i += di + carry;
        if (i >= seq) i -= seq;      // batch wrap (i resets; bucket only needs i,j)
    }
}

extern "C" void kernel_launch(void* const* d_in, const int* in_sizes, int n_in,
                              void* d_out, int out_size, void* d_ws, size_t ws_size,
                              hipStream_t stream) {
    // Inputs per setup_inputs() order: batch_size (int), seq_len (int), W (float32)
    const int* p_seq = (const int*)d_in[1];
    const float* W = (const float*)d_in[2];
    float4* out = (float4*)d_out;

    const unsigned long long n_rows = (unsigned long long)out_size / DIM_OUT;

    // Memory-bound: cap grid ~2048 blocks, grid-stride the rest (G11).
    unsigned long long blocks_needed = (n_rows + 7) / 8;
    int blocks = (int)(blocks_needed < 2048ull ? blocks_needed : 2048ull);
    if (blocks < 1) blocks = 1;

    rpe_kernel<<<blocks, 256, 0, stream>>>(p_seq, W, out, n_rows);
}

// Round 11
// 105.849 us; speedup vs baseline: 1.7007x; 1.7007x over previous
//
#include <hip/hip_runtime.h>

#define R_MAX 32
#define DIM_OUT 128
#define N_R 66              // 2*R_MAX + 2
#define DIM_IN 139          // 2*N_R + 1 + N_S

typedef float f32x4 __attribute__((ext_vector_type(4)));

// out[bi, i, j, d] = W[d, N_R + clip(i-j+32,0,64)] + (W[d,32] + W[d,132] + W[d,138])
// 94% of (i,j) have saturated bucket (0 or 64) -> two per-thread constant float4s.
// Hot loops are pure register stores (fillBuffer shape, ~6.8 TB/s on this chip).
__global__ __launch_bounds__(256) void rpe_kernel(const int* __restrict__ p_seq,
                                                  const float* __restrict__ W,
                                                  f32x4* __restrict__ out,
                                                  unsigned long long n_rows) {
    const unsigned seq = (unsigned)*p_seq;
    const unsigned tid = threadIdx.x;
    const unsigned lane = tid & 31;          // column group: floats [lane*4, lane*4+4)
    const float* w0 = W + (size_t)(lane * 4) * DIM_IN;

    // Per-thread constants (W is 71 KB, L2-resident; ~20 scalar loads once).
    float cst[4];
    f32x4 vhi, vlo;
    #pragma unroll
    for (int k = 0; k < 4; ++k) {
        const float* w = w0 + (size_t)k * DIM_IN;
        // reference association: (W_pos[:,R_MAX] + w_mask) + W_chain[:,2S+1]
        cst[k] = (w[R_MAX] + w[2 * N_R]) + w[DIM_IN - 1];
        vhi[k] = w[N_R + 2 * R_MAX] + cst[k];   // bucket 64 (j <= i-32)
        vlo[k] = w[N_R + 0] + cst[k];           // bucket 0  (j >= i+32)
    }

    const unsigned n_irows = (unsigned)(n_rows / seq);  // batch * seq
    const unsigned CPR = 2;                              // chunks per i-row
    const unsigned total_chunks = n_irows * CPR;

    for (unsigned chunk = blockIdx.x; chunk < total_chunks; chunk += gridDim.x) {
        const unsigned irow = chunk / CPR;
        const unsigned half = chunk - irow * CPR;
        const int i = (int)(irow % seq);
        const int j0 = (int)((half * seq) / CPR);
        const int j1 = (int)(((half + 1) * seq) / CPR);

        // j < i-31  -> bucket 64 (vhi); j in [i-31, i+31] -> band; j >= i+32 -> bucket 0 (vlo)
        int e1 = i - 31; e1 = e1 < j0 ? j0 : (e1 > j1 ? j1 : e1);
        int e2 = i + 32; e2 = e2 < j0 ? j0 : (e2 > j1 ? j1 : e2);

        f32x4* __restrict__ base = out + (size_t)irow * seq * (DIM_OUT / 4);

        // region 1: pure store stream of vhi
        for (int f = j0 * 32 + (int)tid; f < e1 * 32; f += 256)
            __builtin_nontemporal_store(vhi, base + f);

        // region 2: 65-wide band, direct W lookup (tiny fraction; L2-hit loads)
        for (int f = e1 * 32 + (int)tid; f < e2 * 32; f += 256) {
            const int j = f >> 5;
            const int b = i - j + R_MAX;            // in [1, 63]
            f32x4 v;
            v[0] = w0[0 * DIM_IN + N_R + b] + cst[0];
            v[1] = w0[1 * DIM_IN + N_R + b] + cst[1];
            v[2] = w0[2 * DIM_IN + N_R + b] + cst[2];
            v[3] = w0[3 * DIM_IN + N_R + b] + cst[3];
            __builtin_nontemporal_store(v, base + f);
        }

        // region 3: pure store stream of vlo
        for (int f = e2 * 32 + (int)tid; f < j1 * 32; f += 256)
            __builtin_nontemporal_store(vlo, base + f);
    }
}

extern "C" void kernel_launch(void* const* d_in, const int* in_sizes, int n_in,
                              void* d_out, int out_size, void* d_ws, size_t ws_size,
                              hipStream_t stream) {
    // Inputs per setup_inputs() order: batch_size (int), seq_len (int), W (float32)
    const int* p_seq = (const int*)d_in[1];
    const float* W = (const float*)d_in[2];
    f32x4* out = (f32x4*)d_out;

    const unsigned long long n_rows = (unsigned long long)out_size / DIM_OUT;

    // 2048 blocks: for seq=1024 that's exactly one 256 KB chunk per block,
    // 8 blocks/CU (no LDS), device-side chunk-stride loop handles other shapes.
    rpe_kernel<<<2048, 256, 0, stream>>>(p_seq, W, out, n_rows);
}